// Round 13
// baseline (226.032 us; speedup 1.0000x reference)
//
#include <hip/hip_runtime.h>
#include <stdint.h>

#define NTOK 16384

typedef __attribute__((ext_vector_type(8))) short short8;
typedef __attribute__((ext_vector_type(4))) float f32x4;
typedef __attribute__((ext_vector_type(16))) float f32x16;

// round-to-nearest-even f32 -> bf16 (bit pattern as short)
__device__ __forceinline__ short f2bf_rne(float f) {
  union { float f; unsigned u; } a; a.f = f;
  unsigned r = a.u + 0x7fffu + ((a.u >> 16) & 1u);
  return (short)(r >> 16);
}

// compiler-managed v_exp_f32 (raw asm bypasses the trans-op hazard recognizer)
__device__ __forceinline__ float fast_exp2(float x) {
#if __has_builtin(__builtin_amdgcn_exp2f)
  return __builtin_amdgcn_exp2f(x);
#else
  return exp2f(x);
#endif
}

// hazard-safe packed f32x2 -> bf16x2: round-half-up (+0x8000) then v_perm_b32
// picks the two high halves. 3 interlocked VALU ops, no inline asm (R11's asm
// cvt_pk NaN'd; R12's __float22bfloat162_rn cost ~160cyc/half-tile of VALU).
__device__ __forceinline__ unsigned pack_rn(float lo, float hi) {
  union { float f; unsigned u; } a, b;
  a.f = lo; b.f = hi;
  return __builtin_amdgcn_perm(b.u + 0x8000u, a.u + 0x8000u, 0x07060302u);
}

// sigma: involution on 0..31 swapping [4-7]<->[8-11] and [20-23]<->[24-27].
// Storing K row k at slot sigma(k) makes the 32x32 QK^T output's C-rows land
// so that exp'd P packs sequentially into the PV A-fragment (no cross-lane).
__device__ __forceinline__ int sigma32(int s) {
  int t = (s >> 2) & 3;
  return (t == 1 || t == 2) ? (s ^ 12) : s;
}

// ---------------- projection: Q and K in one pass ([N][8] bf16 rows) ----
// K pre-scaled by 1/ln2 (v_exp_f32 = 2^x) and stored sigma-permuted.
__global__ __launch_bounds__(256) void proj_qk_kernel(
    const float* __restrict__ x,
    const float* __restrict__ Wq, const float* __restrict__ bq,
    const float* __restrict__ Wk, const float* __restrict__ bk,
    short* __restrict__ Qp, short* __restrict__ Kp)
{
  __shared__ float sWq[512], sWk[512], sbq[8], sbk[8];
  const int tid = threadIdx.x;
  for (int i = tid; i < 512; i += 256) { sWq[i] = Wq[i]; sWk[i] = Wk[i]; }
  if (tid < 8) { sbq[tid] = bq[tid]; sbk[tid] = bk[tid]; }
  __syncthreads();

  const int n = blockIdx.x * 256 + tid;
  float xv[64];
#pragma unroll
  for (int c = 0; c < 64; ++c) xv[c] = x[c * NTOK + n];

  short8 qv, kv;
#pragma unroll
  for (int d = 0; d < 8; ++d) {
    float qa = sbq[d], ka = sbk[d];
#pragma unroll
    for (int c = 0; c < 64; c += 4) {
      f32x4 wq = *reinterpret_cast<const f32x4*>(&sWq[d * 64 + c]);
      f32x4 wk = *reinterpret_cast<const f32x4*>(&sWk[d * 64 + c]);
      qa += wq[0]*xv[c] + wq[1]*xv[c+1] + wq[2]*xv[c+2] + wq[3]*xv[c+3];
      ka += wk[0]*xv[c] + wk[1]*xv[c+1] + wk[2]*xv[c+2] + wk[3]*xv[c+3];
    }
    qv[d] = f2bf_rne(qa);
    kv[d] = f2bf_rne(ka * 1.44269504f);
  }
  *reinterpret_cast<short8*>(Qp + (size_t)n * 8) = qv;
  const int slot = (n & ~31) | sigma32(n & 31);
  *reinterpret_cast<short8*>(Kp + (size_t)slot * 8) = kv;
}

// ---------------- projection: V in fragment-major layout ----------------
// VF[frag][lane][e], frag=(n>>4)*2+(c>>5), lane=((n>>3)&1)*32+(c&31), e=n&7
// == the exact 32x32x16 B-operand register image, so the attention kernel
// loads each V fragment as ONE contiguous 1KB coalesced read.
__global__ __launch_bounds__(256) void proj_v_kernel(
    const float* __restrict__ x,
    const float* __restrict__ Wv, const float* __restrict__ bv,
    short* __restrict__ VF)
{
  __shared__ float sW[64 * 65];   // +1 pad: kills the 64-way bank conflict
  __shared__ float sx[64][32];
  __shared__ float sb[64];
  const int tid = threadIdx.x;
  const int n0 = blockIdx.x * 32;

  for (int i = tid; i < 4096; i += 256) sW[(i >> 6) * 65 + (i & 63)] = Wv[i];
  if (tid < 64) sb[tid] = bv[tid];
  for (int i = tid; i < 2048; i += 256) {
    const int r = i >> 5, col = i & 31;
    sx[r][col] = x[(size_t)r * NTOK + n0 + col];
  }
  __syncthreads();

  const int c   = tid & 63;
  const int oct = tid >> 6;

  float v[8];
  const float bias = sb[c];
#pragma unroll
  for (int j = 0; j < 8; ++j) v[j] = bias;

  for (int cp = 0; cp < 64; ++cp) {
    const float wv = sW[c * 65 + cp];          // 2-way bank alias: free
    const float* xr = &sx[cp][oct * 8];        // wave-uniform: broadcast
#pragma unroll
    for (int j = 0; j < 8; ++j) v[j] += wv * xr[j];
  }

  const int n    = n0 + oct * 8;
  const int frag = (n >> 4) * 2 + (c >> 5);
  const int lane = ((n >> 3) & 1) * 32 + (c & 31);
  short8 ov;
#pragma unroll
  for (int j = 0; j < 8; ++j) ov[j] = f2bf_rne(v[j]);
  *reinterpret_cast<short8*>(VF + (size_t)frag * 512 + lane * 8) = ov;
}

// ---------------- fused attention: 32x32x16, split-K, 2-deep S pipeline -
// Wave owns 32 q-rows. Swapped QK^T (A=K sigma-permuted, B=Q zero-padded
// d8->16); exp'd P packs sequentially into PV A-frags; V frags are 1KB
// contiguous reads from fragment-major VF. Pipeline: QK for half h+1 issues
// BEFORE the exp/pack/PV of half h (hides QK latency under ~180cyc of VALU);
// K loads issue early-phase, V loads late-phase (after buffer consumed),
// each covered by ~200cyc of compute. s_setprio(1) wraps the PV cluster
// (T5: waves are independent, no barriers). All prefetches clamped in-slice.
__global__ __launch_bounds__(256, 4) void attn_split_kernel(
    const short* __restrict__ Qp, const short* __restrict__ Kp,
    const short* __restrict__ VF,
    float* __restrict__ part, float* __restrict__ lsums, int splits)
{
  const int tid  = threadIdx.x;
  const int w    = tid >> 6;
  const int lane = tid & 63;
  const int hi   = lane >> 5;
  const int ln   = lane & 31;
  const int s    = blockIdx.x;
  const int qw   = blockIdx.y * 4 + w;   // 0..511
  const int q0   = qw * 32;

  const short8 zero8 = {0,0,0,0,0,0,0,0};
  f32x16 zf16;
#pragma unroll
  for (int i = 0; i < 16; ++i) zf16[i] = 0.f;

  // Q fragment: B[k=8hi+e][q=ln]; hi half zero (d=8 padded to K=16)
  short8 qf = hi ? zero8
                 : *reinterpret_cast<const short8*>(Qp + (size_t)(q0 + ln) * 8);

  f32x16 acc0 = zf16, acc1 = zf16;   // c 0-31 / c 32-63
  float lsum = 0.f;

  const int kvlen = NTOK / splits;
  const int kv_lo = s * kvlen;
  const int nh    = kvlen / 32;      // 32-key half-tiles (even, >=2)

  const short* KP0 = Kp + ((size_t)kv_lo + ln) * 8;       // half h: +h*256
  const short* VF0 = VF + (size_t)kv_lo * 64 + lane * 8;  // half h: +h*2048

  auto loadK = [&](int h, short8& kf) {
    kf = *reinterpret_cast<const short8*>(KP0 + (size_t)h * 256);
  };
  auto loadV = [&](int h, short8 (&vf)[4]) {
    const short* vp = VF0 + (size_t)h * 2048;
#pragma unroll
    for (int j = 0; j < 4; ++j)
      vf[j] = *reinterpret_cast<const short8*>(vp + j * 512);
  };

  // exp + round-pack + pairwise lsum tree for one half-tile's S
  auto expPack = [&](const f32x16& sv, unsigned (&u)[8]) {
    float t[8];
#pragma unroll
    for (int j = 0; j < 8; ++j) {
      float e0 = fast_exp2(sv[2*j]);
      float e1 = fast_exp2(sv[2*j+1]);
      u[j] = pack_rn(e0, e1);
      t[j] = e0 + e1;
    }
    lsum += ((t[0]+t[1]) + (t[2]+t[3])) + ((t[4]+t[5]) + (t[6]+t[7]));
  };

  auto pvHalf = [&](const unsigned (&u)[8], const short8 (&vf)[4]) {
    union { unsigned u32[4]; short8 s8; } pa0, pa1;
#pragma unroll
    for (int j = 0; j < 4; ++j) { pa0.u32[j] = u[j]; pa1.u32[j] = u[4+j]; }
    __builtin_amdgcn_s_setprio(1);
    acc0 = __builtin_amdgcn_mfma_f32_32x32x16_bf16(pa0.s8, vf[0], acc0, 0, 0, 0);
    acc1 = __builtin_amdgcn_mfma_f32_32x32x16_bf16(pa0.s8, vf[1], acc1, 0, 0, 0);
    acc0 = __builtin_amdgcn_mfma_f32_32x32x16_bf16(pa1.s8, vf[2], acc0, 0, 0, 0);
    acc1 = __builtin_amdgcn_mfma_f32_32x32x16_bf16(pa1.s8, vf[3], acc1, 0, 0, 0);
    __builtin_amdgcn_s_setprio(0);
  };

  // prologue: halves 0,1 resident; S(0) in flight
  short8 kA, kB, vA[4], vB[4];
  loadK(0, kA); loadV(0, vA);
  loadK(1, kB); loadV(1, vB);
  f32x16 svA = __builtin_amdgcn_mfma_f32_32x32x16_bf16(kA, qf, zf16, 0, 0, 0);
  f32x16 svB;

  for (int h = 0; h < nh; h += 2) {
    // ---- half h (consume svA, vA; issue S(h+1), loads h+2) ----
    svB = __builtin_amdgcn_mfma_f32_32x32x16_bf16(kB, qf, zf16, 0, 0, 0);
    { const int hp = (h + 2 < nh) ? h + 2 : nh - 1; loadK(hp, kA); }
    unsigned u[8];
    expPack(svA, u);
    pvHalf(u, vA);
    { const int hp = (h + 2 < nh) ? h + 2 : nh - 1; loadV(hp, vA); }

    // ---- half h+1 (consume svB, vB; issue S(h+2), loads h+3) ----
    svA = __builtin_amdgcn_mfma_f32_32x32x16_bf16(kA, qf, zf16, 0, 0, 0);
    { const int hp = (h + 3 < nh) ? h + 3 : nh - 1; loadK(hp, kB); }
    unsigned u2[8];
    expPack(svB, u2);
    pvHalf(u2, vB);
    { const int hp = (h + 3 < nh) ? h + 3 : nh - 1; loadV(hp, vB); }
  }

  // full row denominator for q = ln (hi halves cover disjoint key sets)
  lsum += __shfl_xor(lsum, 32);
  if (lane < 32)
    lsums[(size_t)s * NTOK + q0 + ln] = lsum;

  // partial O, q-major [q][64c]; C layout: row=(r&3)+8*(r>>2)+4*hi, col=ln
  float* pp = part + ((size_t)s * NTOK + q0) * 64;
#pragma unroll
  for (int r = 0; r < 16; ++r) {
    const int qrow = (r & 3) + 8 * (r >> 2) + 4 * hi;
    pp[qrow * 64 + ln]      = acc0[r];
    pp[qrow * 64 + 32 + ln] = acc1[r];
  }
}

// ---------------- reduce: sum partials, normalize, gamma*O + x ----------
__global__ __launch_bounds__(256) void reduce_kernel(
    const float* __restrict__ part, const float* __restrict__ lsums,
    const float* __restrict__ x, const float* __restrict__ gamma,
    float* __restrict__ out, int splits)
{
  __shared__ float tile[64][65];
  __shared__ float linv[64];
  const int tid = threadIdx.x;
  const int qb  = blockIdx.x;

  // phase 1: coalesced q-major reads, sum over splits
  {
    const int qloc = tid >> 2, c0 = (tid & 3) * 16;
    f32x4 a[4] = {{0,0,0,0},{0,0,0,0},{0,0,0,0},{0,0,0,0}};
    float ls = 0.f;
    for (int s = 0; s < splits; ++s) {
      const float* p = part + ((size_t)s * NTOK + qb * 64 + qloc) * 64 + c0;
#pragma unroll
      for (int j = 0; j < 4; ++j)
        a[j] += *reinterpret_cast<const f32x4*>(p + 4 * j);
      if ((tid & 3) == 0)
        ls += lsums[(size_t)s * NTOK + qb * 64 + qloc];
    }
#pragma unroll
    for (int j = 0; j < 4; ++j)
#pragma unroll
      for (int e = 0; e < 4; ++e)
        tile[qloc][c0 + 4 * j + e] = a[j][e];
    if ((tid & 3) == 0) linv[qloc] = 1.f / ls;
  }
  __syncthreads();

  // phase 2: c-major writes (transposed via LDS)
  const int c = tid >> 2, qs = (tid & 3) * 16;
  const float gam = gamma[0];
#pragma unroll
  for (int i = 0; i < 16; ++i) {
    const int q = qs + i;
    const size_t idx = (size_t)c * NTOK + qb * 64 + q;
    out[idx] = gam * tile[q][c] * linv[q] + x[idx];
  }
}

extern "C" void kernel_launch(void* const* d_in, const int* in_sizes, int n_in,
                              void* d_out, int out_size, void* d_ws, size_t ws_size,
                              hipStream_t stream) {
  const float* x     = (const float*)d_in[0];
  const float* Wq    = (const float*)d_in[1];
  const float* bq    = (const float*)d_in[2];
  const float* Wk    = (const float*)d_in[3];
  const float* bk    = (const float*)d_in[4];
  const float* Wv    = (const float*)d_in[5];
  const float* bv    = (const float*)d_in[6];
  const float* gamma = (const float*)d_in[7];
  float* out = (float*)d_out;

  short* Qp = (short*)d_ws;                 // [N][8]  bf16  (256 KB)
  short* Kp = Qp + (size_t)NTOK * 8;        // [N][8]  bf16  (256 KB), sigma rows
  short* VF = Kp + (size_t)NTOK * 8;        // frag-major V (2 MB)
  float* part  = (float*)(VF + (size_t)64 * NTOK);       // [s][q][64c]

  const size_t base_bytes = (size_t)NTOK * 8 * 2 * 2 + (size_t)64 * NTOK * 2;
  auto fits = [&](int sp) {
    return base_bytes + (size_t)sp * NTOK * 64 * 4 + (size_t)sp * NTOK * 4 <= ws_size;
  };

  // splits=8: 4096 waves = 4/SIMD; grid (8,128) puts split s on XCD s.
  int splits = 8;
  while (splits > 2 && !fits(splits)) splits >>= 1;

  float* lsums = part + (size_t)splits * NTOK * 64;

  proj_qk_kernel<<<NTOK / 256, 256, 0, stream>>>(x, Wq, bq, Wk, bk, Qp, Kp);
  proj_v_kernel<<<NTOK / 32, 256, 0, stream>>>(x, Wv, bv, VF);
  attn_split_kernel<<<dim3(splits, 128), 256, 0, stream>>>(Qp, Kp, VF, part, lsums, splits);
  reduce_kernel<<<NTOK / 64, 256, 0, stream>>>(part, lsums, x, gamma, out, splits);
}

// Round 14
// 90.237 us; speedup vs baseline: 2.5049x; 2.5049x over previous
//
#include <hip/hip_runtime.h>
#include <stdint.h>

#define NTOK 16384

typedef __attribute__((ext_vector_type(8))) short short8;
typedef __attribute__((ext_vector_type(4))) float f32x4;
typedef __attribute__((ext_vector_type(16))) float f32x16;

// round-to-nearest-even f32 -> bf16 (bit pattern as short)
__device__ __forceinline__ short f2bf_rne(float f) {
  union { float f; unsigned u; } a; a.f = f;
  unsigned r = a.u + 0x7fffu + ((a.u >> 16) & 1u);
  return (short)(r >> 16);
}

// compiler-managed v_exp_f32 (raw asm bypasses the trans-op hazard recognizer)
__device__ __forceinline__ float fast_exp2(float x) {
#if __has_builtin(__builtin_amdgcn_exp2f)
  return __builtin_amdgcn_exp2f(x);
#else
  return exp2f(x);
#endif
}

// hazard-safe packed f32x2 -> bf16x2: round-half-up (+0x8000) then v_perm_b32
// takes the two high halves. 3 interlocked VALU ops, no inline asm (R11's asm
// cvt_pk NaN'd; R12's __float22bfloat162_rn costs ~5 ops/value).
// P >= 0 and finite here, so round-half-up vs RNE is a <=2^-17 bias: harmless.
__device__ __forceinline__ unsigned pack_rn(float lo, float hi) {
  union { float f; unsigned u; } a, b;
  a.f = lo; b.f = hi;
  return __builtin_amdgcn_perm(b.u + 0x8000u, a.u + 0x8000u, 0x07060302u);
}

// sigma: involution on 0..31 swapping [4-7]<->[8-11] and [20-23]<->[24-27].
// Storing K row k at slot sigma(k) makes the 32x32 QK^T output's C-rows land
// so that exp'd P packs sequentially into the PV A-fragment (no cross-lane).
__device__ __forceinline__ int sigma32(int s) {
  int t = (s >> 2) & 3;
  return (t == 1 || t == 2) ? (s ^ 12) : s;
}

// ---------------- projection: Q and K in one pass ([N][8] bf16 rows) ----
// K pre-scaled by 1/ln2 (v_exp_f32 = 2^x) and stored sigma-permuted.
__global__ __launch_bounds__(256) void proj_qk_kernel(
    const float* __restrict__ x,
    const float* __restrict__ Wq, const float* __restrict__ bq,
    const float* __restrict__ Wk, const float* __restrict__ bk,
    short* __restrict__ Qp, short* __restrict__ Kp)
{
  __shared__ float sWq[512], sWk[512], sbq[8], sbk[8];
  const int tid = threadIdx.x;
  for (int i = tid; i < 512; i += 256) { sWq[i] = Wq[i]; sWk[i] = Wk[i]; }
  if (tid < 8) { sbq[tid] = bq[tid]; sbk[tid] = bk[tid]; }
  __syncthreads();

  const int n = blockIdx.x * 256 + tid;
  float xv[64];
#pragma unroll
  for (int c = 0; c < 64; ++c) xv[c] = x[c * NTOK + n];

  short8 qv, kv;
#pragma unroll
  for (int d = 0; d < 8; ++d) {
    float qa = sbq[d], ka = sbk[d];
#pragma unroll
    for (int c = 0; c < 64; c += 4) {
      f32x4 wq = *reinterpret_cast<const f32x4*>(&sWq[d * 64 + c]);
      f32x4 wk = *reinterpret_cast<const f32x4*>(&sWk[d * 64 + c]);
      qa += wq[0]*xv[c] + wq[1]*xv[c+1] + wq[2]*xv[c+2] + wq[3]*xv[c+3];
      ka += wk[0]*xv[c] + wk[1]*xv[c+1] + wk[2]*xv[c+2] + wk[3]*xv[c+3];
    }
    qv[d] = f2bf_rne(qa);
    kv[d] = f2bf_rne(ka * 1.44269504f);
  }
  *reinterpret_cast<short8*>(Qp + (size_t)n * 8) = qv;
  const int slot = (n & ~31) | sigma32(n & 31);
  *reinterpret_cast<short8*>(Kp + (size_t)slot * 8) = kv;
}

// ---------------- projection: V in fragment-major layout ----------------
// VF[frag][lane][e], frag=(n>>4)*2+(c>>5), lane=((n>>3)&1)*32+(c&31), e=n&7
// == the exact 32x32x16 B-operand register image, so the attention kernel
// loads each V fragment as ONE contiguous 1KB coalesced read.
__global__ __launch_bounds__(256) void proj_v_kernel(
    const float* __restrict__ x,
    const float* __restrict__ Wv, const float* __restrict__ bv,
    short* __restrict__ VF)
{
  __shared__ float sW[64 * 65];   // +1 pad: kills the 64-way bank conflict
  __shared__ float sx[64][32];
  __shared__ float sb[64];
  const int tid = threadIdx.x;
  const int n0 = blockIdx.x * 32;

  for (int i = tid; i < 4096; i += 256) sW[(i >> 6) * 65 + (i & 63)] = Wv[i];
  if (tid < 64) sb[tid] = bv[tid];
  for (int i = tid; i < 2048; i += 256) {
    const int r = i >> 5, col = i & 31;
    sx[r][col] = x[(size_t)r * NTOK + n0 + col];
  }
  __syncthreads();

  const int c   = tid & 63;
  const int oct = tid >> 6;

  float v[8];
  const float bias = sb[c];
#pragma unroll
  for (int j = 0; j < 8; ++j) v[j] = bias;

  for (int cp = 0; cp < 64; ++cp) {
    const float wv = sW[c * 65 + cp];          // 2-way bank alias: free
    const float* xr = &sx[cp][oct * 8];        // wave-uniform: broadcast
#pragma unroll
    for (int j = 0; j < 8; ++j) v[j] += wv * xr[j];
  }

  const int n    = n0 + oct * 8;
  const int frag = (n >> 4) * 2 + (c >> 5);
  const int lane = ((n >> 3) & 1) * 32 + (c & 31);
  short8 ov;
#pragma unroll
  for (int j = 0; j < 8; ++j) ov[j] = f2bf_rne(v[j]);
  *reinterpret_cast<short8*>(VF + (size_t)frag * 512 + lane * 8) = ov;
}

// ---------------- fused attention: 32x32x16, split-K, 2-deep S pipeline -
// Wave owns 32 q-rows. Swapped QK^T (A=K sigma-permuted, B=Q zero-padded
// d8->16); exp'd P packs sequentially into PV A-frags; V frags are 1KB
// contiguous reads from fragment-major VF. Pipeline (R12-proven): QK for
// half h+1 issues BEFORE exp/pack/PV of half h; K loads early-phase, V loads
// late-phase. All prefetches clamped in-slice. NEW vs R12: perm-based pack
// (-~80 VALU ops/tile) and a raw s_barrier per tile-pair to keep the block's
// 4 waves converged so they share L1 on the common V tiles (V stream is
// ~1GB of L2 traffic ~= 31us floor; L1 sharing cuts it ~4x). Raw s_barrier
// has no memory semantics -> in-flight prefetches stay in flight; it is a
// perf hint only, correctness never depends on convergence.
// NOTE: no s_setprio here - R13 showed it (or its live-range effect) caused
// a 525MB scratch spill on this structure.
__global__ __launch_bounds__(256, 4) void attn_split_kernel(
    const short* __restrict__ Qp, const short* __restrict__ Kp,
    const short* __restrict__ VF,
    float* __restrict__ part, float* __restrict__ lsums, int splits)
{
  const int tid  = threadIdx.x;
  const int w    = tid >> 6;
  const int lane = tid & 63;
  const int hi   = lane >> 5;
  const int ln   = lane & 31;
  const int s    = blockIdx.x;
  const int qw   = blockIdx.y * 4 + w;   // 0..511
  const int q0   = qw * 32;

  const short8 zero8 = {0,0,0,0,0,0,0,0};
  f32x16 zf16;
#pragma unroll
  for (int i = 0; i < 16; ++i) zf16[i] = 0.f;

  // Q fragment: B[k=8hi+e][q=ln]; hi half zero (d=8 padded to K=16)
  short8 qf = hi ? zero8
                 : *reinterpret_cast<const short8*>(Qp + (size_t)(q0 + ln) * 8);

  f32x16 acc0 = zf16, acc1 = zf16;   // c 0-31 / c 32-63
  float lsum = 0.f;

  const int kvlen = NTOK / splits;
  const int kv_lo = s * kvlen;
  const int nh    = kvlen / 32;      // 32-key half-tiles (even, >=2)

  const short* KP0 = Kp + ((size_t)kv_lo + ln) * 8;       // half h: +h*256
  const short* VF0 = VF + (size_t)kv_lo * 64 + lane * 8;  // half h: +h*2048

  auto loadK = [&](int h, short8& kf) {
    kf = *reinterpret_cast<const short8*>(KP0 + (size_t)h * 256);
  };
  auto loadV = [&](int h, short8 (&vf)[4]) {
    const short* vp = VF0 + (size_t)h * 2048;
#pragma unroll
    for (int j = 0; j < 4; ++j)
      vf[j] = *reinterpret_cast<const short8*>(vp + j * 512);
  };

  // exp + perm-pack + pairwise lsum tree for one half-tile's S
  auto expPack = [&](const f32x16& sv, unsigned (&u)[8]) {
    float t[8];
#pragma unroll
    for (int j = 0; j < 8; ++j) {
      float e0 = fast_exp2(sv[2*j]);
      float e1 = fast_exp2(sv[2*j+1]);
      u[j] = pack_rn(e0, e1);
      t[j] = e0 + e1;
    }
    lsum += ((t[0]+t[1]) + (t[2]+t[3])) + ((t[4]+t[5]) + (t[6]+t[7]));
  };

  auto pvHalf = [&](const unsigned (&u)[8], const short8 (&vf)[4]) {
    union { unsigned u32[4]; short8 s8; } pa0, pa1;
#pragma unroll
    for (int j = 0; j < 4; ++j) { pa0.u32[j] = u[j]; pa1.u32[j] = u[4+j]; }
    acc0 = __builtin_amdgcn_mfma_f32_32x32x16_bf16(pa0.s8, vf[0], acc0, 0, 0, 0);
    acc1 = __builtin_amdgcn_mfma_f32_32x32x16_bf16(pa0.s8, vf[1], acc1, 0, 0, 0);
    acc0 = __builtin_amdgcn_mfma_f32_32x32x16_bf16(pa1.s8, vf[2], acc0, 0, 0, 0);
    acc1 = __builtin_amdgcn_mfma_f32_32x32x16_bf16(pa1.s8, vf[3], acc1, 0, 0, 0);
  };

  // prologue: halves 0,1 resident; S(0) in flight
  short8 kA, kB, vA[4], vB[4];
  loadK(0, kA); loadV(0, vA);
  loadK(1, kB); loadV(1, vB);
  f32x16 svA = __builtin_amdgcn_mfma_f32_32x32x16_bf16(kA, qf, zf16, 0, 0, 0);
  f32x16 svB;

  for (int h = 0; h < nh; h += 2) {
    // keep the block's 4 waves tile-converged (L1 sharing of K/V tiles)
    __builtin_amdgcn_s_barrier();

    // ---- half h (consume svA, vA; issue S(h+1), loads h+2) ----
    svB = __builtin_amdgcn_mfma_f32_32x32x16_bf16(kB, qf, zf16, 0, 0, 0);
    { const int hp = (h + 2 < nh) ? h + 2 : nh - 1; loadK(hp, kA); }
    unsigned u[8];
    expPack(svA, u);
    pvHalf(u, vA);
    { const int hp = (h + 2 < nh) ? h + 2 : nh - 1; loadV(hp, vA); }

    // ---- half h+1 (consume svB, vB; issue S(h+2), loads h+3) ----
    svA = __builtin_amdgcn_mfma_f32_32x32x16_bf16(kA, qf, zf16, 0, 0, 0);
    { const int hp = (h + 3 < nh) ? h + 3 : nh - 1; loadK(hp, kB); }
    unsigned u2[8];
    expPack(svB, u2);
    pvHalf(u2, vB);
    { const int hp = (h + 3 < nh) ? h + 3 : nh - 1; loadV(hp, vB); }
  }

  // full row denominator for q = ln (hi halves cover disjoint key sets)
  lsum += __shfl_xor(lsum, 32);
  if (lane < 32)
    lsums[(size_t)s * NTOK + q0 + ln] = lsum;

  // partial O, q-major [q][64c]; C layout: row=(r&3)+8*(r>>2)+4*hi, col=ln
  float* pp = part + ((size_t)s * NTOK + q0) * 64;
#pragma unroll
  for (int r = 0; r < 16; ++r) {
    const int qrow = (r & 3) + 8 * (r >> 2) + 4 * hi;
    pp[qrow * 64 + ln]      = acc0[r];
    pp[qrow * 64 + 32 + ln] = acc1[r];
  }
}

// ---------------- reduce: sum partials, normalize, gamma*O + x ----------
__global__ __launch_bounds__(256) void reduce_kernel(
    const float* __restrict__ part, const float* __restrict__ lsums,
    const float* __restrict__ x, const float* __restrict__ gamma,
    float* __restrict__ out, int splits)
{
  __shared__ float tile[64][65];
  __shared__ float linv[64];
  const int tid = threadIdx.x;
  const int qb  = blockIdx.x;

  // phase 1: coalesced q-major reads, sum over splits
  {
    const int qloc = tid >> 2, c0 = (tid & 3) * 16;
    f32x4 a[4] = {{0,0,0,0},{0,0,0,0},{0,0,0,0},{0,0,0,0}};
    float ls = 0.f;
    for (int s = 0; s < splits; ++s) {
      const float* p = part + ((size_t)s * NTOK + qb * 64 + qloc) * 64 + c0;
#pragma unroll
      for (int j = 0; j < 4; ++j)
        a[j] += *reinterpret_cast<const f32x4*>(p + 4 * j);
      if ((tid & 3) == 0)
        ls += lsums[(size_t)s * NTOK + qb * 64 + qloc];
    }
#pragma unroll
    for (int j = 0; j < 4; ++j)
#pragma unroll
      for (int e = 0; e < 4; ++e)
        tile[qloc][c0 + 4 * j + e] = a[j][e];
    if ((tid & 3) == 0) linv[qloc] = 1.f / ls;
  }
  __syncthreads();

  // phase 2: c-major writes (transposed via LDS)
  const int c = tid >> 2, qs = (tid & 3) * 16;
  const float gam = gamma[0];
#pragma unroll
  for (int i = 0; i < 16; ++i) {
    const int q = qs + i;
    const size_t idx = (size_t)c * NTOK + qb * 64 + q;
    out[idx] = gam * tile[q][c] * linv[q] + x[idx];
  }
}

extern "C" void kernel_launch(void* const* d_in, const int* in_sizes, int n_in,
                              void* d_out, int out_size, void* d_ws, size_t ws_size,
                              hipStream_t stream) {
  const float* x     = (const float*)d_in[0];
  const float* Wq    = (const float*)d_in[1];
  const float* bq    = (const float*)d_in[2];
  const float* Wk    = (const float*)d_in[3];
  const float* bk    = (const float*)d_in[4];
  const float* Wv    = (const float*)d_in[5];
  const float* bv    = (const float*)d_in[6];
  const float* gamma = (const float*)d_in[7];
  float* out = (float*)d_out;

  short* Qp = (short*)d_ws;                 // [N][8]  bf16  (256 KB)
  short* Kp = Qp + (size_t)NTOK * 8;        // [N][8]  bf16  (256 KB), sigma rows
  short* VF = Kp + (size_t)NTOK * 8;        // frag-major V (2 MB)
  float* part  = (float*)(VF + (size_t)64 * NTOK);       // [s][q][64c]

  const size_t base_bytes = (size_t)NTOK * 8 * 2 * 2 + (size_t)64 * NTOK * 2;
  auto fits = [&](int sp) {
    return base_bytes + (size_t)sp * NTOK * 64 * 4 + (size_t)sp * NTOK * 4 <= ws_size;
  };

  // splits=8: 4096 waves = 4/SIMD; grid (8,128) puts split s on XCD s.
  int splits = 8;
  while (splits > 2 && !fits(splits)) splits >>= 1;

  float* lsums = part + (size_t)splits * NTOK * 64;

  proj_qk_kernel<<<NTOK / 256, 256, 0, stream>>>(x, Wq, bq, Wk, bk, Qp, Kp);
  proj_v_kernel<<<NTOK / 32, 256, 0, stream>>>(x, Wv, bv, VF);
  attn_split_kernel<<<dim3(splits, 128), 256, 0, stream>>>(Qp, Kp, VF, part, lsums, splits);
  reduce_kernel<<<NTOK / 64, 256, 0, stream>>>(part, lsums, x, gamma, out, splits);
}

// Round 15
// 81.033 us; speedup vs baseline: 2.7894x; 1.1136x over previous
//
#include <hip/hip_runtime.h>
#include <stdint.h>

#define NTOK 16384

typedef __attribute__((ext_vector_type(8))) short short8;
typedef __attribute__((ext_vector_type(4))) float f32x4;
typedef __attribute__((ext_vector_type(16))) float f32x16;

// round-to-nearest-even f32 -> bf16 (bit pattern as short)
__device__ __forceinline__ short f2bf_rne(float f) {
  union { float f; unsigned u; } a; a.f = f;
  unsigned r = a.u + 0x7fffu + ((a.u >> 16) & 1u);
  return (short)(r >> 16);
}

// compiler-managed v_exp_f32 (raw asm bypasses the trans-op hazard recognizer)
__device__ __forceinline__ float fast_exp2(float x) {
#if __has_builtin(__builtin_amdgcn_exp2f)
  return __builtin_amdgcn_exp2f(x);
#else
  return exp2f(x);
#endif
}

// hazard-safe packed f32x2 -> bf16x2: round-half-up (+0x8000) then v_perm_b32
// takes the two high halves. 3 interlocked VALU ops, no inline asm.
// P >= 0 and finite here, so round-half-up vs RNE is a <=2^-17 bias: harmless.
__device__ __forceinline__ unsigned pack_rn(float lo, float hi) {
  union { float f; unsigned u; } a, b;
  a.f = lo; b.f = hi;
  return __builtin_amdgcn_perm(b.u + 0x8000u, a.u + 0x8000u, 0x07060302u);
}

// sigma: involution on 0..31 swapping [4-7]<->[8-11] and [20-23]<->[24-27].
// Storing K row k at slot sigma(k) makes the 32x32 QK^T output's C-rows land
// so that exp'd P packs sequentially into the PV A-fragment (no cross-lane).
__device__ __forceinline__ int sigma32(int s) {
  int t = (s >> 2) & 3;
  return (t == 1 || t == 2) ? (s ^ 12) : s;
}

// ---------------- projection: Q and K in one pass ([N][8] bf16 rows) ----
// K pre-scaled by 1/ln2 (v_exp_f32 = 2^x) and stored sigma-permuted.
__global__ __launch_bounds__(256) void proj_qk_kernel(
    const float* __restrict__ x,
    const float* __restrict__ Wq, const float* __restrict__ bq,
    const float* __restrict__ Wk, const float* __restrict__ bk,
    short* __restrict__ Qp, short* __restrict__ Kp)
{
  __shared__ float sWq[512], sWk[512], sbq[8], sbk[8];
  const int tid = threadIdx.x;
  for (int i = tid; i < 512; i += 256) { sWq[i] = Wq[i]; sWk[i] = Wk[i]; }
  if (tid < 8) { sbq[tid] = bq[tid]; sbk[tid] = bk[tid]; }
  __syncthreads();

  const int n = blockIdx.x * 256 + tid;
  float xv[64];
#pragma unroll
  for (int c = 0; c < 64; ++c) xv[c] = x[c * NTOK + n];

  short8 qv, kv;
#pragma unroll
  for (int d = 0; d < 8; ++d) {
    float qa = sbq[d], ka = sbk[d];
#pragma unroll
    for (int c = 0; c < 64; c += 4) {
      f32x4 wq = *reinterpret_cast<const f32x4*>(&sWq[d * 64 + c]);
      f32x4 wk = *reinterpret_cast<const f32x4*>(&sWk[d * 64 + c]);
      qa += wq[0]*xv[c] + wq[1]*xv[c+1] + wq[2]*xv[c+2] + wq[3]*xv[c+3];
      ka += wk[0]*xv[c] + wk[1]*xv[c+1] + wk[2]*xv[c+2] + wk[3]*xv[c+3];
    }
    qv[d] = f2bf_rne(qa);
    kv[d] = f2bf_rne(ka * 1.44269504f);
  }
  *reinterpret_cast<short8*>(Qp + (size_t)n * 8) = qv;
  const int slot = (n & ~31) | sigma32(n & 31);
  *reinterpret_cast<short8*>(Kp + (size_t)slot * 8) = kv;
}

// ---------------- projection: V in fragment-major layout ----------------
// VF[frag][lane][e], frag=(n>>4)*2+(c>>5), lane=((n>>3)&1)*32+(c&31), e=n&7
// == the exact 32x32x16 B-operand register image, so the attention kernel
// loads each V fragment as ONE contiguous 1KB coalesced read.
__global__ __launch_bounds__(256) void proj_v_kernel(
    const float* __restrict__ x,
    const float* __restrict__ Wv, const float* __restrict__ bv,
    short* __restrict__ VF)
{
  __shared__ float sW[64 * 65];   // +1 pad: kills the 64-way bank conflict
  __shared__ float sx[64][32];
  __shared__ float sb[64];
  const int tid = threadIdx.x;
  const int n0 = blockIdx.x * 32;

  for (int i = tid; i < 4096; i += 256) sW[(i >> 6) * 65 + (i & 63)] = Wv[i];
  if (tid < 64) sb[tid] = bv[tid];
  for (int i = tid; i < 2048; i += 256) {
    const int r = i >> 5, col = i & 31;
    sx[r][col] = x[(size_t)r * NTOK + n0 + col];
  }
  __syncthreads();

  const int c   = tid & 63;
  const int oct = tid >> 6;

  float v[8];
  const float bias = sb[c];
#pragma unroll
  for (int j = 0; j < 8; ++j) v[j] = bias;

  for (int cp = 0; cp < 64; ++cp) {
    const float wv = sW[c * 65 + cp];          // 2-way bank alias: free
    const float* xr = &sx[cp][oct * 8];        // wave-uniform: broadcast
#pragma unroll
    for (int j = 0; j < 8; ++j) v[j] += wv * xr[j];
  }

  const int n    = n0 + oct * 8;
  const int frag = (n >> 4) * 2 + (c >> 5);
  const int lane = ((n >> 3) & 1) * 32 + (c & 31);
  short8 ov;
#pragma unroll
  for (int j = 0; j < 8; ++j) ov[j] = f2bf_rne(v[j]);
  *reinterpret_cast<short8*>(VF + (size_t)frag * 512 + lane * 8) = ov;
}

// ---------------- fused attention: split-K WITHIN the block -------------
// Block = 8 waves, all owning the SAME 32 q-rows; wave w covers key slice
// [w*2048, (w+1)*2048). Inner loop is R14's proven 2-deep pipeline verbatim
// (QK for h+1 before exp/pack/PV of h; K early / V late prefetch, clamped).
// Epilogue: partial O + lsum to padded LDS, __syncthreads, 8-way reduce,
// normalize, gamma*O + x, direct c-major store. This deletes the separate
// reduce kernel and the 67MB part-write/read round-trip (R14: ~10-13us).
// No mid-loop barrier: waves read disjoint slices (no L1-sharing rationale;
// phase-locking 8 waves only hurts VALU/MFMA pipe mixing).
__global__ __launch_bounds__(512, 4) void attn_fused_kernel(
    const short* __restrict__ Qp, const short* __restrict__ Kp,
    const short* __restrict__ VF,
    const float* __restrict__ x, const float* __restrict__ gamma,
    float* __restrict__ out)
{
  __shared__ float lacc[8 * 2080];    // [w][q=32][65]  (pad kills conflicts)
  __shared__ float slsum[8 * 32];     // [w][q]

  const int tid  = threadIdx.x;
  const int w    = tid >> 6;          // key-slice 0..7
  const int lane = tid & 63;
  const int hi   = lane >> 5;
  const int ln   = lane & 31;
  const int q0   = blockIdx.x * 32;

  const short8 zero8 = {0,0,0,0,0,0,0,0};
  f32x16 zf16;
#pragma unroll
  for (int i = 0; i < 16; ++i) zf16[i] = 0.f;

  // Q fragment: B[k=8hi+e][q=ln]; hi half zero (d=8 padded to K=16)
  short8 qf = hi ? zero8
                 : *reinterpret_cast<const short8*>(Qp + (size_t)(q0 + ln) * 8);

  f32x16 acc0 = zf16, acc1 = zf16;   // c 0-31 / c 32-63
  float lsum = 0.f;

  const int kvlen = NTOK / 8;
  const int kv_lo = w * kvlen;
  const int nh    = kvlen / 32;      // 64 half-tiles of 32 keys

  const short* KP0 = Kp + ((size_t)kv_lo + ln) * 8;       // half h: +h*256
  const short* VF0 = VF + (size_t)kv_lo * 64 + lane * 8;  // half h: +h*2048

  auto loadK = [&](int h, short8& kf) {
    kf = *reinterpret_cast<const short8*>(KP0 + (size_t)h * 256);
  };
  auto loadV = [&](int h, short8 (&vf)[4]) {
    const short* vp = VF0 + (size_t)h * 2048;
#pragma unroll
    for (int j = 0; j < 4; ++j)
      vf[j] = *reinterpret_cast<const short8*>(vp + j * 512);
  };

  auto expPack = [&](const f32x16& sv, unsigned (&u)[8]) {
    float t[8];
#pragma unroll
    for (int j = 0; j < 8; ++j) {
      float e0 = fast_exp2(sv[2*j]);
      float e1 = fast_exp2(sv[2*j+1]);
      u[j] = pack_rn(e0, e1);
      t[j] = e0 + e1;
    }
    lsum += ((t[0]+t[1]) + (t[2]+t[3])) + ((t[4]+t[5]) + (t[6]+t[7]));
  };

  auto pvHalf = [&](const unsigned (&u)[8], const short8 (&vf)[4]) {
    union { unsigned u32[4]; short8 s8; } pa0, pa1;
#pragma unroll
    for (int j = 0; j < 4; ++j) { pa0.u32[j] = u[j]; pa1.u32[j] = u[4+j]; }
    acc0 = __builtin_amdgcn_mfma_f32_32x32x16_bf16(pa0.s8, vf[0], acc0, 0, 0, 0);
    acc1 = __builtin_amdgcn_mfma_f32_32x32x16_bf16(pa0.s8, vf[1], acc1, 0, 0, 0);
    acc0 = __builtin_amdgcn_mfma_f32_32x32x16_bf16(pa1.s8, vf[2], acc0, 0, 0, 0);
    acc1 = __builtin_amdgcn_mfma_f32_32x32x16_bf16(pa1.s8, vf[3], acc1, 0, 0, 0);
  };

  // prologue: halves 0,1 resident; S(0) in flight
  short8 kA, kB, vA[4], vB[4];
  loadK(0, kA); loadV(0, vA);
  loadK(1, kB); loadV(1, vB);
  f32x16 svA = __builtin_amdgcn_mfma_f32_32x32x16_bf16(kA, qf, zf16, 0, 0, 0);
  f32x16 svB;

  for (int h = 0; h < nh; h += 2) {
    // ---- half h (consume svA, vA; issue S(h+1), loads h+2) ----
    svB = __builtin_amdgcn_mfma_f32_32x32x16_bf16(kB, qf, zf16, 0, 0, 0);
    { const int hp = (h + 2 < nh) ? h + 2 : nh - 1; loadK(hp, kA); }
    unsigned u[8];
    expPack(svA, u);
    pvHalf(u, vA);
    { const int hp = (h + 2 < nh) ? h + 2 : nh - 1; loadV(hp, vA); }

    // ---- half h+1 (consume svB, vB; issue S(h+2), loads h+3) ----
    svA = __builtin_amdgcn_mfma_f32_32x32x16_bf16(kA, qf, zf16, 0, 0, 0);
    { const int hp = (h + 3 < nh) ? h + 3 : nh - 1; loadK(hp, kB); }
    unsigned u2[8];
    expPack(svB, u2);
    pvHalf(u2, vB);
    { const int hp = (h + 3 < nh) ? h + 3 : nh - 1; loadV(hp, vB); }
  }

  // ---- epilogue: stage partials in LDS ----
  // C layout: qrow=(r&3)+8*(r>>2)+4*hi, col=ln (acc0) / 32+ln (acc1)
  float* la = &lacc[w * 2080];
#pragma unroll
  for (int r = 0; r < 16; ++r) {
    const int qrow = (r & 3) + 8 * (r >> 2) + 4 * hi;
    la[qrow * 65 + ln]      = acc0[r];
    la[qrow * 65 + 32 + ln] = acc1[r];
  }
  lsum += __shfl_xor(lsum, 32);      // combine hi halves (disjoint keys)
  if (lane < 32) slsum[w * 32 + ln] = lsum;
  __syncthreads();

  // ---- 8-way reduce + normalize + residual, c-major store ----
  const int q = tid & 31;            // same q for all k-iterations
  float ls = 0.f;
#pragma unroll
  for (int w2 = 0; w2 < 8; ++w2) ls += slsum[w2 * 32 + q];
  const float inv = 1.f / ls;
  const float gam = gamma[0];

#pragma unroll
  for (int k = 0; k < 4; ++k) {
    const int c = (tid >> 5) + k * 16;
    float sum = 0.f;
#pragma unroll
    for (int w2 = 0; w2 < 8; ++w2) sum += lacc[w2 * 2080 + q * 65 + c];
    const size_t idx = (size_t)c * NTOK + q0 + q;
    out[idx] = gam * sum * inv + x[idx];
  }
}

extern "C" void kernel_launch(void* const* d_in, const int* in_sizes, int n_in,
                              void* d_out, int out_size, void* d_ws, size_t ws_size,
                              hipStream_t stream) {
  const float* x     = (const float*)d_in[0];
  const float* Wq    = (const float*)d_in[1];
  const float* bq    = (const float*)d_in[2];
  const float* Wk    = (const float*)d_in[3];
  const float* bk    = (const float*)d_in[4];
  const float* Wv    = (const float*)d_in[5];
  const float* bv    = (const float*)d_in[6];
  const float* gamma = (const float*)d_in[7];
  float* out = (float*)d_out;

  short* Qp = (short*)d_ws;                 // [N][8]  bf16  (256 KB)
  short* Kp = Qp + (size_t)NTOK * 8;        // [N][8]  bf16  (256 KB), sigma rows
  short* VF = Kp + (size_t)NTOK * 8;        // frag-major V (2 MB)

  proj_qk_kernel<<<NTOK / 256, 256, 0, stream>>>(x, Wq, bq, Wk, bk, Qp, Kp);
  proj_v_kernel<<<NTOK / 32, 256, 0, stream>>>(x, Wv, bv, VF);
  attn_fused_kernel<<<NTOK / 32, 512, 0, stream>>>(Qp, Kp, VF, x, gamma, out);
}

// Round 16
// 80.693 us; speedup vs baseline: 2.8011x; 1.0042x over previous
//
#include <hip/hip_runtime.h>
#include <stdint.h>

#define NTOK 16384

typedef __attribute__((ext_vector_type(8))) short short8;
typedef __attribute__((ext_vector_type(4))) float f32x4;
typedef __attribute__((ext_vector_type(16))) float f32x16;

// round-to-nearest-even f32 -> bf16 (bit pattern as short)
__device__ __forceinline__ short f2bf_rne(float f) {
  union { float f; unsigned u; } a; a.f = f;
  unsigned r = a.u + 0x7fffu + ((a.u >> 16) & 1u);
  return (short)(r >> 16);
}

// compiler-managed v_exp_f32 (raw asm bypasses the trans-op hazard recognizer)
__device__ __forceinline__ float fast_exp2(float x) {
#if __has_builtin(__builtin_amdgcn_exp2f)
  return __builtin_amdgcn_exp2f(x);
#else
  return exp2f(x);
#endif
}

// truncating packed f32x2 -> bf16x2: ONE v_perm_b32 (no rounding adds).
// P >= 0; truncation biases P down by <=2^-8 rel, but the lsum denominator
// is computed from the SAME truncated values (ones-MFMA) -> bias cancels
// exactly in O = (P V) / (P 1).
__device__ __forceinline__ unsigned pack_trunc(float lo, float hi) {
  union { float f; unsigned u; } a, b;
  a.f = lo; b.f = hi;
  return __builtin_amdgcn_perm(b.u, a.u, 0x07060302u);
}

// sigma: involution on 0..31 swapping [4-7]<->[8-11] and [20-23]<->[24-27].
// Storing K row k at slot sigma(k) makes the 32x32 QK^T output's C-rows land
// so that exp'd P packs sequentially into the PV A-fragment (no cross-lane).
__device__ __forceinline__ int sigma32(int s) {
  int t = (s >> 2) & 3;
  return (t == 1 || t == 2) ? (s ^ 12) : s;
}

// ---------------- fused projections: V (frag-major) + Q + K -------------
// Block = 32 tokens. V part: thread (c=tid&63, oct=tid>>6) computes 8
// tokens x 1 channel -> one contiguous short8 into VF (the exact 32x32x16
// B-operand register image; 1KB coalesced loads in attention).
// QK part: thread (qk=tid&15, tp=tid>>4) computes 2 tokens x 1 output dim
// from the same LDS-staged x; K scaled by 1/ln2 and stored sigma-permuted.
__global__ __launch_bounds__(256) void proj_all_kernel(
    const float* __restrict__ x,
    const float* __restrict__ Wq, const float* __restrict__ bq,
    const float* __restrict__ Wk, const float* __restrict__ bk,
    const float* __restrict__ Wv, const float* __restrict__ bv,
    short* __restrict__ Qp, short* __restrict__ Kp, short* __restrict__ VF)
{
  __shared__ float sW[64 * 65];     // Wv, +1 pad
  __shared__ float sx[64][32];
  __shared__ float sb[64];
  __shared__ float sWqk[16 * 65];   // rows 0-7 Wq, 8-15 Wk, +1 pad
  __shared__ float sbqk[16];
  const int tid = threadIdx.x;
  const int n0 = blockIdx.x * 32;

  for (int i = tid; i < 4096; i += 256) sW[(i >> 6) * 65 + (i & 63)] = Wv[i];
  if (tid < 64) sb[tid] = bv[tid];
  for (int i = tid; i < 512; i += 256) {
    sWqk[(i >> 6) * 65 + (i & 63)]       = Wq[i];
    sWqk[((i >> 6) + 8) * 65 + (i & 63)] = Wk[i];
  }
  if (tid < 8)       sbqk[tid] = bq[tid];
  else if (tid < 16) sbqk[tid] = bk[tid - 8];
  for (int i = tid; i < 2048; i += 256) {
    const int r = i >> 5, col = i & 31;
    sx[r][col] = x[(size_t)r * NTOK + n0 + col];
  }
  __syncthreads();

  // ---- V ----
  {
    const int c   = tid & 63;
    const int oct = tid >> 6;
    float v[8];
    const float bias = sb[c];
#pragma unroll
    for (int j = 0; j < 8; ++j) v[j] = bias;
    for (int cp = 0; cp < 64; ++cp) {
      const float wv = sW[c * 65 + cp];
      const float* xr = &sx[cp][oct * 8];
#pragma unroll
      for (int j = 0; j < 8; ++j) v[j] += wv * xr[j];
    }
    const int n    = n0 + oct * 8;
    const int frag = (n >> 4) * 2 + (c >> 5);
    const int lane = ((n >> 3) & 1) * 32 + (c & 31);
    short8 ov;
#pragma unroll
    for (int j = 0; j < 8; ++j) ov[j] = f2bf_rne(v[j]);
    *reinterpret_cast<short8*>(VF + (size_t)frag * 512 + lane * 8) = ov;
  }

  // ---- Q, K ----
  {
    const int qk = tid & 15;     // 0-7: Q dim, 8-15: K dim
    const int tp = tid >> 4;     // tokens tp and tp+16
    float a0 = 0.f, a1 = 0.f;
    for (int cp = 0; cp < 64; ++cp) {
      const float wv = sWqk[qk * 65 + cp];
      a0 += wv * sx[cp][tp];
      a1 += wv * sx[cp][tp + 16];
    }
    const float bias = sbqk[qk];
    if (qk < 8) {
      Qp[(size_t)(n0 + tp) * 8 + qk]      = f2bf_rne(a0 + bias);
      Qp[(size_t)(n0 + tp + 16) * 8 + qk] = f2bf_rne(a1 + bias);
    } else {
      const int d = qk - 8;
      Kp[(size_t)(n0 + sigma32(tp)) * 8 + d] =
          f2bf_rne((a0 + bias) * 1.44269504f);
      Kp[(size_t)(n0 + sigma32(tp + 16)) * 8 + d] =
          f2bf_rne((a1 + bias) * 1.44269504f);
    }
  }
}

// ---------------- fused attention: split-K WITHIN the block -------------
// Block = 8 waves, all owning the SAME 32 q-rows; wave w covers key slice
// [w*2048, (w+1)*2048). R15-proven 2-deep pipeline (QK for h+1 before
// exp/pack/PV of h; K early / V late prefetch, clamped). NEW vs R15:
// (1) truncating 1-op pack (was 3 ops/pair); (2) lsum rides a ones-MFMA
// into acc_l (deletes the 15-add tree + end shuffle; denominator now sums
// the SAME truncated bf16 P as the numerator -> truncation bias cancels).
// Epilogue: partials to padded LDS, 8-way reduce, normalize, gamma*O + x.
// NOTE: no s_setprio (R13: spill on this structure).
__global__ __launch_bounds__(512, 4) void attn_fused_kernel(
    const short* __restrict__ Qp, const short* __restrict__ Kp,
    const short* __restrict__ VF,
    const float* __restrict__ x, const float* __restrict__ gamma,
    float* __restrict__ out)
{
  __shared__ float lacc[8 * 2080];    // [w][q=32][65]  (pad kills conflicts)
  __shared__ float slsum[8 * 32];     // [w][q]

  const int tid  = threadIdx.x;
  const int w    = tid >> 6;          // key-slice 0..7
  const int lane = tid & 63;
  const int hi   = lane >> 5;
  const int ln   = lane & 31;
  const int q0   = blockIdx.x * 32;

  const short8 zero8 = {0,0,0,0,0,0,0,0};
  const short  one_bf = (short)0x3F80;
  const short8 ones8 = {one_bf,one_bf,one_bf,one_bf,one_bf,one_bf,one_bf,one_bf};
  f32x16 zf16;
#pragma unroll
  for (int i = 0; i < 16; ++i) zf16[i] = 0.f;

  // Q fragment: B[k=8hi+e][q=ln]; hi half zero (d=8 padded to K=16)
  short8 qf = hi ? zero8
                 : *reinterpret_cast<const short8*>(Qp + (size_t)(q0 + ln) * 8);

  f32x16 acc0 = zf16, acc1 = zf16;   // c 0-31 / c 32-63
  f32x16 acc_l = zf16;               // row sum of truncated P (ones-MFMA)

  const int kvlen = NTOK / 8;
  const int kv_lo = w * kvlen;
  const int nh    = kvlen / 32;      // 64 half-tiles of 32 keys

  const short* KP0 = Kp + ((size_t)kv_lo + ln) * 8;       // half h: +h*256
  const short* VF0 = VF + (size_t)kv_lo * 64 + lane * 8;  // half h: +h*2048

  auto loadK = [&](int h, short8& kf) {
    kf = *reinterpret_cast<const short8*>(KP0 + (size_t)h * 256);
  };
  auto loadV = [&](int h, short8 (&vf)[4]) {
    const short* vp = VF0 + (size_t)h * 2048;
#pragma unroll
    for (int j = 0; j < 4; ++j)
      vf[j] = *reinterpret_cast<const short8*>(vp + j * 512);
  };

  auto expPack = [&](const f32x16& sv, unsigned (&u)[8]) {
#pragma unroll
    for (int j = 0; j < 8; ++j) {
      float e0 = fast_exp2(sv[2*j]);
      float e1 = fast_exp2(sv[2*j+1]);
      u[j] = pack_trunc(e0, e1);
    }
  };

  auto pvHalf = [&](const unsigned (&u)[8], const short8 (&vf)[4]) {
    union { unsigned u32[4]; short8 s8; } pa0, pa1;
#pragma unroll
    for (int j = 0; j < 4; ++j) { pa0.u32[j] = u[j]; pa1.u32[j] = u[4+j]; }
    acc0  = __builtin_amdgcn_mfma_f32_32x32x16_bf16(pa0.s8, vf[0], acc0, 0, 0, 0);
    acc1  = __builtin_amdgcn_mfma_f32_32x32x16_bf16(pa0.s8, vf[1], acc1, 0, 0, 0);
    acc_l = __builtin_amdgcn_mfma_f32_32x32x16_bf16(pa0.s8, ones8, acc_l, 0, 0, 0);
    acc0  = __builtin_amdgcn_mfma_f32_32x32x16_bf16(pa1.s8, vf[2], acc0, 0, 0, 0);
    acc1  = __builtin_amdgcn_mfma_f32_32x32x16_bf16(pa1.s8, vf[3], acc1, 0, 0, 0);
    acc_l = __builtin_amdgcn_mfma_f32_32x32x16_bf16(pa1.s8, ones8, acc_l, 0, 0, 0);
  };

  // prologue: halves 0,1 resident; S(0) in flight
  short8 kA, kB, vA[4], vB[4];
  loadK(0, kA); loadV(0, vA);
  loadK(1, kB); loadV(1, vB);
  f32x16 svA = __builtin_amdgcn_mfma_f32_32x32x16_bf16(kA, qf, zf16, 0, 0, 0);
  f32x16 svB;

  for (int h = 0; h < nh; h += 2) {
    // ---- half h (consume svA, vA; issue S(h+1), loads h+2) ----
    svB = __builtin_amdgcn_mfma_f32_32x32x16_bf16(kB, qf, zf16, 0, 0, 0);
    { const int hp = (h + 2 < nh) ? h + 2 : nh - 1; loadK(hp, kA); }
    unsigned u[8];
    expPack(svA, u);
    pvHalf(u, vA);
    { const int hp = (h + 2 < nh) ? h + 2 : nh - 1; loadV(hp, vA); }

    // ---- half h+1 (consume svB, vB; issue S(h+2), loads h+3) ----
    svA = __builtin_amdgcn_mfma_f32_32x32x16_bf16(kA, qf, zf16, 0, 0, 0);
    { const int hp = (h + 3 < nh) ? h + 3 : nh - 1; loadK(hp, kB); }
    unsigned u2[8];
    expPack(svB, u2);
    pvHalf(u2, vB);
    { const int hp = (h + 3 < nh) ? h + 3 : nh - 1; loadV(hp, vB); }
  }

  // ---- epilogue: stage partials in LDS ----
  // C layout: qrow=(r&3)+8*(r>>2)+4*hi, col=ln (acc0) / 32+ln (acc1).
  // acc_l[r] = lsum[qrow] (identical across ln; covers this wave's keys).
  float* la = &lacc[w * 2080];
#pragma unroll
  for (int r = 0; r < 16; ++r) {
    const int qrow = (r & 3) + 8 * (r >> 2) + 4 * hi;
    la[qrow * 65 + ln]      = acc0[r];
    la[qrow * 65 + 32 + ln] = acc1[r];
  }
  if (ln == 0) {
#pragma unroll
    for (int r = 0; r < 16; ++r) {
      const int qrow = (r & 3) + 8 * (r >> 2) + 4 * hi;
      slsum[w * 32 + qrow] = acc_l[r];
    }
  }
  __syncthreads();

  // ---- 8-way reduce + normalize + residual, c-major store ----
  const int q = tid & 31;
  float ls = 0.f;
#pragma unroll
  for (int w2 = 0; w2 < 8; ++w2) ls += slsum[w2 * 32 + q];
  const float inv = 1.f / ls;
  const float gam = gamma[0];

#pragma unroll
  for (int k = 0; k < 4; ++k) {
    const int c = (tid >> 5) + k * 16;
    float sum = 0.f;
#pragma unroll
    for (int w2 = 0; w2 < 8; ++w2) sum += lacc[w2 * 2080 + q * 65 + c];
    const size_t idx = (size_t)c * NTOK + q0 + q;
    out[idx] = gam * sum * inv + x[idx];
  }
}

extern "C" void kernel_launch(void* const* d_in, const int* in_sizes, int n_in,
                              void* d_out, int out_size, void* d_ws, size_t ws_size,
                              hipStream_t stream) {
  const float* x     = (const float*)d_in[0];
  const float* Wq    = (const float*)d_in[1];
  const float* bq    = (const float*)d_in[2];
  const float* Wk    = (const float*)d_in[3];
  const float* bk    = (const float*)d_in[4];
  const float* Wv    = (const float*)d_in[5];
  const float* bv    = (const float*)d_in[6];
  const float* gamma = (const float*)d_in[7];
  float* out = (float*)d_out;

  short* Qp = (short*)d_ws;                 // [N][8]  bf16  (256 KB)
  short* Kp = Qp + (size_t)NTOK * 8;        // [N][8]  bf16  (256 KB), sigma rows
  short* VF = Kp + (size_t)NTOK * 8;        // frag-major V (2 MB)

  proj_all_kernel<<<NTOK / 32, 256, 0, stream>>>(x, Wq, bq, Wk, bk, Wv, bv,
                                                 Qp, Kp, VF);
  attn_fused_kernel<<<NTOK / 32, 512, 0, stream>>>(Qp, Kp, VF, x, gamma, out);
}

// Round 17
// 73.159 us; speedup vs baseline: 3.0896x; 1.1030x over previous
//
#include <hip/hip_runtime.h>
#include <stdint.h>

#define NTOK 16384

typedef __attribute__((ext_vector_type(8))) short short8;
typedef __attribute__((ext_vector_type(4))) float f32x4;
typedef __attribute__((ext_vector_type(16))) float f32x16;

// round-to-nearest-even f32 -> bf16 (bit pattern as short)
__device__ __forceinline__ short f2bf_rne(float f) {
  union { float f; unsigned u; } a; a.f = f;
  unsigned r = a.u + 0x7fffu + ((a.u >> 16) & 1u);
  return (short)(r >> 16);
}

// compiler-managed v_exp_f32 (raw asm bypasses the trans-op hazard recognizer)
__device__ __forceinline__ float fast_exp2(float x) {
#if __has_builtin(__builtin_amdgcn_exp2f)
  return __builtin_amdgcn_exp2f(x);
#else
  return exp2f(x);
#endif
}

// truncating packed f32x2 -> bf16x2: ONE v_perm_b32 (no rounding adds).
// P >= 0; truncation biases the PV numerator down <=2^-9 relative, a ~7e-4
// systematic output bias at |O|<=0.35 -- far under the 0.099 threshold
// (validated in R16 at absmax 0.0156).
__device__ __forceinline__ unsigned pack_trunc(float lo, float hi) {
  union { float f; unsigned u; } a, b;
  a.f = lo; b.f = hi;
  return __builtin_amdgcn_perm(b.u, a.u, 0x07060302u);
}

// sigma: involution on 0..31 swapping [4-7]<->[8-11] and [20-23]<->[24-27].
// Storing K row k at slot sigma(k) makes the 32x32 QK^T output's C-rows land
// so that exp'd P packs sequentially into the PV A-fragment (no cross-lane).
__device__ __forceinline__ int sigma32(int s) {
  int t = (s >> 2) & 3;
  return (t == 1 || t == 2) ? (s ^ 12) : s;
}

// ---------------- fused projections: V (frag-major) + Q + K -------------
// Block = 32 tokens. V part: thread (c=tid&63, oct=tid>>6) computes 8
// tokens x 1 channel -> one contiguous short8 into VF (the exact 32x32x16
// B-operand register image; 1KB coalesced loads in attention).
// QK part: thread (qk=tid&15, tp=tid>>4) computes 2 tokens x 1 output dim
// from the same LDS-staged x; K scaled by 1/ln2 and stored sigma-permuted.
__global__ __launch_bounds__(256) void proj_all_kernel(
    const float* __restrict__ x,
    const float* __restrict__ Wq, const float* __restrict__ bq,
    const float* __restrict__ Wk, const float* __restrict__ bk,
    const float* __restrict__ Wv, const float* __restrict__ bv,
    short* __restrict__ Qp, short* __restrict__ Kp, short* __restrict__ VF)
{
  __shared__ float sW[64 * 65];     // Wv, +1 pad
  __shared__ float sx[64][32];
  __shared__ float sb[64];
  __shared__ float sWqk[16 * 65];   // rows 0-7 Wq, 8-15 Wk, +1 pad
  __shared__ float sbqk[16];
  const int tid = threadIdx.x;
  const int n0 = blockIdx.x * 32;

  for (int i = tid; i < 4096; i += 256) sW[(i >> 6) * 65 + (i & 63)] = Wv[i];
  if (tid < 64) sb[tid] = bv[tid];
  for (int i = tid; i < 512; i += 256) {
    sWqk[(i >> 6) * 65 + (i & 63)]       = Wq[i];
    sWqk[((i >> 6) + 8) * 65 + (i & 63)] = Wk[i];
  }
  if (tid < 8)       sbqk[tid] = bq[tid];
  else if (tid < 16) sbqk[tid] = bk[tid - 8];
  for (int i = tid; i < 2048; i += 256) {
    const int r = i >> 5, col = i & 31;
    sx[r][col] = x[(size_t)r * NTOK + n0 + col];
  }
  __syncthreads();

  // ---- V ----
  {
    const int c   = tid & 63;
    const int oct = tid >> 6;
    float v[8];
    const float bias = sb[c];
#pragma unroll
    for (int j = 0; j < 8; ++j) v[j] = bias;
    for (int cp = 0; cp < 64; ++cp) {
      const float wv = sW[c * 65 + cp];
      const float* xr = &sx[cp][oct * 8];
#pragma unroll
      for (int j = 0; j < 8; ++j) v[j] += wv * xr[j];
    }
    const int n    = n0 + oct * 8;
    const int frag = (n >> 4) * 2 + (c >> 5);
    const int lane = ((n >> 3) & 1) * 32 + (c & 31);
    short8 ov;
#pragma unroll
    for (int j = 0; j < 8; ++j) ov[j] = f2bf_rne(v[j]);
    *reinterpret_cast<short8*>(VF + (size_t)frag * 512 + lane * 8) = ov;
  }

  // ---- Q, K ----
  {
    const int qk = tid & 15;     // 0-7: Q dim, 8-15: K dim
    const int tp = tid >> 4;     // tokens tp and tp+16
    float a0 = 0.f, a1 = 0.f;
    for (int cp = 0; cp < 64; ++cp) {
      const float wv = sWqk[qk * 65 + cp];
      a0 += wv * sx[cp][tp];
      a1 += wv * sx[cp][tp + 16];
    }
    const float bias = sbqk[qk];
    if (qk < 8) {
      Qp[(size_t)(n0 + tp) * 8 + qk]      = f2bf_rne(a0 + bias);
      Qp[(size_t)(n0 + tp + 16) * 8 + qk] = f2bf_rne(a1 + bias);
    } else {
      const int d = qk - 8;
      Kp[(size_t)(n0 + sigma32(tp)) * 8 + d] =
          f2bf_rne((a0 + bias) * 1.44269504f);
      Kp[(size_t)(n0 + sigma32(tp + 16)) * 8 + d] =
          f2bf_rne((a1 + bias) * 1.44269504f);
    }
  }
}

// ---------------- fused attention: split-K WITHIN the block -------------
// Block = 8 waves, all owning the SAME 32 q-rows; wave w covers key slice
// [w*2048, (w+1)*2048). R15-proven 2-deep pipeline (QK for h+1 before
// exp/pack/PV of h; K early / V late prefetch, clamped) with R15's f32
// pairwise-tree lsum (R16's ones-MFMA lsum put 2 extra MFMAs on the
// critical path: VALU busy -14us but dur +6us -- the deleted VALU was
// latency filler, the added MFMA was dependent-path). Trunc 1-op pack kept.
// Epilogue: partials to padded LDS, 8-way reduce, normalize, gamma*O + x.
// NOTE: no s_setprio (R13: spill on this structure).
__global__ __launch_bounds__(512, 4) void attn_fused_kernel(
    const short* __restrict__ Qp, const short* __restrict__ Kp,
    const short* __restrict__ VF,
    const float* __restrict__ x, const float* __restrict__ gamma,
    float* __restrict__ out)
{
  __shared__ float lacc[8 * 2080];    // [w][q=32][65]  (pad kills conflicts)
  __shared__ float slsum[8 * 32];     // [w][q]

  const int tid  = threadIdx.x;
  const int w    = tid >> 6;          // key-slice 0..7
  const int lane = tid & 63;
  const int hi   = lane >> 5;
  const int ln   = lane & 31;
  const int q0   = blockIdx.x * 32;

  const short8 zero8 = {0,0,0,0,0,0,0,0};
  f32x16 zf16;
#pragma unroll
  for (int i = 0; i < 16; ++i) zf16[i] = 0.f;

  // Q fragment: B[k=8hi+e][q=ln]; hi half zero (d=8 padded to K=16)
  short8 qf = hi ? zero8
                 : *reinterpret_cast<const short8*>(Qp + (size_t)(q0 + ln) * 8);

  f32x16 acc0 = zf16, acc1 = zf16;   // c 0-31 / c 32-63
  float lsum = 0.f;

  const int kvlen = NTOK / 8;
  const int kv_lo = w * kvlen;
  const int nh    = kvlen / 32;      // 64 half-tiles of 32 keys

  const short* KP0 = Kp + ((size_t)kv_lo + ln) * 8;       // half h: +h*256
  const short* VF0 = VF + (size_t)kv_lo * 64 + lane * 8;  // half h: +h*2048

  auto loadK = [&](int h, short8& kf) {
    kf = *reinterpret_cast<const short8*>(KP0 + (size_t)h * 256);
  };
  auto loadV = [&](int h, short8 (&vf)[4]) {
    const short* vp = VF0 + (size_t)h * 2048;
#pragma unroll
    for (int j = 0; j < 4; ++j)
      vf[j] = *reinterpret_cast<const short8*>(vp + j * 512);
  };

  // exp + trunc-pack + pairwise f32 lsum tree for one half-tile's S
  auto expPack = [&](const f32x16& sv, unsigned (&u)[8]) {
    float t[8];
#pragma unroll
    for (int j = 0; j < 8; ++j) {
      float e0 = fast_exp2(sv[2*j]);
      float e1 = fast_exp2(sv[2*j+1]);
      u[j] = pack_trunc(e0, e1);
      t[j] = e0 + e1;
    }
    lsum += ((t[0]+t[1]) + (t[2]+t[3])) + ((t[4]+t[5]) + (t[6]+t[7]));
  };

  auto pvHalf = [&](const unsigned (&u)[8], const short8 (&vf)[4]) {
    union { unsigned u32[4]; short8 s8; } pa0, pa1;
#pragma unroll
    for (int j = 0; j < 4; ++j) { pa0.u32[j] = u[j]; pa1.u32[j] = u[4+j]; }
    acc0 = __builtin_amdgcn_mfma_f32_32x32x16_bf16(pa0.s8, vf[0], acc0, 0, 0, 0);
    acc1 = __builtin_amdgcn_mfma_f32_32x32x16_bf16(pa0.s8, vf[1], acc1, 0, 0, 0);
    acc0 = __builtin_amdgcn_mfma_f32_32x32x16_bf16(pa1.s8, vf[2], acc0, 0, 0, 0);
    acc1 = __builtin_amdgcn_mfma_f32_32x32x16_bf16(pa1.s8, vf[3], acc1, 0, 0, 0);
  };

  // prologue: halves 0,1 resident; S(0) in flight
  short8 kA, kB, vA[4], vB[4];
  loadK(0, kA); loadV(0, vA);
  loadK(1, kB); loadV(1, vB);
  f32x16 svA = __builtin_amdgcn_mfma_f32_32x32x16_bf16(kA, qf, zf16, 0, 0, 0);
  f32x16 svB;

  for (int h = 0; h < nh; h += 2) {
    // ---- half h (consume svA, vA; issue S(h+1), loads h+2) ----
    svB = __builtin_amdgcn_mfma_f32_32x32x16_bf16(kB, qf, zf16, 0, 0, 0);
    { const int hp = (h + 2 < nh) ? h + 2 : nh - 1; loadK(hp, kA); }
    unsigned u[8];
    expPack(svA, u);
    pvHalf(u, vA);
    { const int hp = (h + 2 < nh) ? h + 2 : nh - 1; loadV(hp, vA); }

    // ---- half h+1 (consume svB, vB; issue S(h+2), loads h+3) ----
    svA = __builtin_amdgcn_mfma_f32_32x32x16_bf16(kA, qf, zf16, 0, 0, 0);
    { const int hp = (h + 3 < nh) ? h + 3 : nh - 1; loadK(hp, kB); }
    unsigned u2[8];
    expPack(svB, u2);
    pvHalf(u2, vB);
    { const int hp = (h + 3 < nh) ? h + 3 : nh - 1; loadV(hp, vB); }
  }

  // ---- epilogue: stage partials in LDS ----
  // C layout: qrow=(r&3)+8*(r>>2)+4*hi, col=ln (acc0) / 32+ln (acc1)
  float* la = &lacc[w * 2080];
#pragma unroll
  for (int r = 0; r < 16; ++r) {
    const int qrow = (r & 3) + 8 * (r >> 2) + 4 * hi;
    la[qrow * 65 + ln]      = acc0[r];
    la[qrow * 65 + 32 + ln] = acc1[r];
  }
  lsum += __shfl_xor(lsum, 32);      // combine hi halves (disjoint keys)
  if (lane < 32) slsum[w * 32 + ln] = lsum;
  __syncthreads();

  // ---- 8-way reduce + normalize + residual, c-major store ----
  const int q = tid & 31;
  float ls = 0.f;
#pragma unroll
  for (int w2 = 0; w2 < 8; ++w2) ls += slsum[w2 * 32 + q];
  const float inv = 1.f / ls;
  const float gam = gamma[0];

#pragma unroll
  for (int k = 0; k < 4; ++k) {
    const int c = (tid >> 5) + k * 16;
    float sum = 0.f;
#pragma unroll
    for (int w2 = 0; w2 < 8; ++w2) sum += lacc[w2 * 2080 + q * 65 + c];
    const size_t idx = (size_t)c * NTOK + q0 + q;
    out[idx] = gam * sum * inv + x[idx];
  }
}

extern "C" void kernel_launch(void* const* d_in, const int* in_sizes, int n_in,
                              void* d_out, int out_size, void* d_ws, size_t ws_size,
                              hipStream_t stream) {
  const float* x     = (const float*)d_in[0];
  const float* Wq    = (const float*)d_in[1];
  const float* bq    = (const float*)d_in[2];
  const float* Wk    = (const float*)d_in[3];
  const float* bk    = (const float*)d_in[4];
  const float* Wv    = (const float*)d_in[5];
  const float* bv    = (const float*)d_in[6];
  const float* gamma = (const float*)d_in[7];
  float* out = (float*)d_out;

  short* Qp = (short*)d_ws;                 // [N][8]  bf16  (256 KB)
  short* Kp = Qp + (size_t)NTOK * 8;        // [N][8]  bf16  (256 KB), sigma rows
  short* VF = Kp + (size_t)NTOK * 8;        // frag-major V (2 MB)

  proj_all_kernel<<<NTOK / 32, 256, 0, stream>>>(x, Wq, bq, Wk, bk, Wv, bv,
                                                 Qp, Kp, VF);
  attn_fused_kernel<<<NTOK / 32, 512, 0, stream>>>(Qp, Kp, VF, x, gamma, out);
}

// Round 18
// 65.200 us; speedup vs baseline: 3.4668x; 1.1221x over previous
//
#include <hip/hip_runtime.h>
#include <stdint.h>

#define NTOK 16384

typedef __attribute__((ext_vector_type(8))) short short8;
typedef __attribute__((ext_vector_type(4))) float f32x4;
typedef __attribute__((ext_vector_type(16))) float f32x16;

// round-to-nearest-even f32 -> bf16 (bit pattern as short)
__device__ __forceinline__ short f2bf_rne(float f) {
  union { float f; unsigned u; } a; a.f = f;
  unsigned r = a.u + 0x7fffu + ((a.u >> 16) & 1u);
  return (short)(r >> 16);
}

// compiler-managed v_exp_f32 (raw asm bypasses the trans-op hazard recognizer)
__device__ __forceinline__ float fast_exp2(float x) {
#if __has_builtin(__builtin_amdgcn_exp2f)
  return __builtin_amdgcn_exp2f(x);
#else
  return exp2f(x);
#endif
}

// pack 4 f32 -> 4 OCP e4m3 bytes in one u32 (2x v_cvt_pk_fp8_f32)
__device__ __forceinline__ unsigned pack_fp8x4(float a, float b, float c, float d) {
  int r = __builtin_amdgcn_cvt_pk_fp8_f32(a, b, 0, false);   // bytes 1:0
  r = __builtin_amdgcn_cvt_pk_fp8_f32(c, d, r, true);        // bytes 3:2
  return (unsigned)r;
}

// sigma: involution on 0..31 swapping [4-7]<->[8-11] and [20-23]<->[24-27].
// Storing K row k at slot sigma(k) makes the 32x32 QK^T output's C-rows land
// so that exp'd P packs sequentially into the PV A-fragment (no cross-lane).
__device__ __forceinline__ int sigma32(int s) {
  int t = (s >> 2) & 3;
  return (t == 1 || t == 2) ? (s ^ 12) : s;
}

// ---------------- fused projections: V (frag-major fp8) + Q + K ---------
// Block = 32 tokens. V part: thread (c=tid&63, oct=tid>>6) computes 8
// tokens x 1 channel -> 8 e4m3 bytes, one contiguous 8B store into VF8
// (the exact 32x32x16 fp8 B-operand register image; per-frag 512B, lane*8).
// QK part: thread (qk=tid&15, tp=tid>>4) computes 2 tokens x 1 output dim;
// K scaled by 1/ln2 and stored sigma-permuted (bf16).
__global__ __launch_bounds__(256) void proj_all_kernel(
    const float* __restrict__ x,
    const float* __restrict__ Wq, const float* __restrict__ bq,
    const float* __restrict__ Wk, const float* __restrict__ bk,
    const float* __restrict__ Wv, const float* __restrict__ bv,
    short* __restrict__ Qp, short* __restrict__ Kp,
    unsigned char* __restrict__ VF8)
{
  __shared__ float sW[64 * 65];     // Wv, +1 pad
  __shared__ float sx[64][32];
  __shared__ float sb[64];
  __shared__ float sWqk[16 * 65];   // rows 0-7 Wq, 8-15 Wk, +1 pad
  __shared__ float sbqk[16];
  const int tid = threadIdx.x;
  const int n0 = blockIdx.x * 32;

  for (int i = tid; i < 4096; i += 256) sW[(i >> 6) * 65 + (i & 63)] = Wv[i];
  if (tid < 64) sb[tid] = bv[tid];
  for (int i = tid; i < 512; i += 256) {
    sWqk[(i >> 6) * 65 + (i & 63)]       = Wq[i];
    sWqk[((i >> 6) + 8) * 65 + (i & 63)] = Wk[i];
  }
  if (tid < 8)       sbqk[tid] = bq[tid];
  else if (tid < 16) sbqk[tid] = bk[tid - 8];
  for (int i = tid; i < 2048; i += 256) {
    const int r = i >> 5, col = i & 31;
    sx[r][col] = x[(size_t)r * NTOK + n0 + col];
  }
  __syncthreads();

  // ---- V (fp8 e4m3) ----
  {
    const int c   = tid & 63;
    const int oct = tid >> 6;
    float v[8];
    const float bias = sb[c];
#pragma unroll
    for (int j = 0; j < 8; ++j) v[j] = bias;
    for (int cp = 0; cp < 64; ++cp) {
      const float wv = sW[c * 65 + cp];
      const float* xr = &sx[cp][oct * 8];
#pragma unroll
      for (int j = 0; j < 8; ++j) v[j] += wv * xr[j];
    }
    const int n    = n0 + oct * 8;
    const int frag = (n >> 4) * 2 + (c >> 5);
    const int lane = ((n >> 3) & 1) * 32 + (c & 31);
    uint2 ov;
    ov.x = pack_fp8x4(v[0], v[1], v[2], v[3]);
    ov.y = pack_fp8x4(v[4], v[5], v[6], v[7]);
    *reinterpret_cast<uint2*>(VF8 + (size_t)frag * 512 + lane * 8) = ov;
  }

  // ---- Q, K (bf16) ----
  {
    const int qk = tid & 15;     // 0-7: Q dim, 8-15: K dim
    const int tp = tid >> 4;     // tokens tp and tp+16
    float a0 = 0.f, a1 = 0.f;
    for (int cp = 0; cp < 64; ++cp) {
      const float wv = sWqk[qk * 65 + cp];
      a0 += wv * sx[cp][tp];
      a1 += wv * sx[cp][tp + 16];
    }
    const float bias = sbqk[qk];
    if (qk < 8) {
      Qp[(size_t)(n0 + tp) * 8 + qk]      = f2bf_rne(a0 + bias);
      Qp[(size_t)(n0 + tp + 16) * 8 + qk] = f2bf_rne(a1 + bias);
    } else {
      const int d = qk - 8;
      Kp[(size_t)(n0 + sigma32(tp)) * 8 + d] =
          f2bf_rne((a0 + bias) * 1.44269504f);
      Kp[(size_t)(n0 + sigma32(tp + 16)) * 8 + d] =
          f2bf_rne((a1 + bias) * 1.44269504f);
    }
  }
}

// ---------------- fused attention: split-K in block, fp8 PV -------------
// Block = 8 waves, all owning the SAME 32 q-rows; wave w covers key slice
// [w*2048, (w+1)*2048). R17-proven 2-deep pipeline (QK bf16 for h+1 before
// exp/pack/PV of h; K early / V late prefetch, clamped). NEW vs R17: PV in
// fp8 (mfma_f32_32x32x16_fp8_fp8) -- V stream through L1 halves (4KB->2KB
// per half-tile; V traffic was the dominant data-path cost), P converts via
// v_cvt_pk_fp8_f32 (8 ops/ht, same count as the perm pack it replaces).
// lsum stays the exact f32 pairwise tree (denominator unaffected by fp8).
// Epilogue: partials to padded LDS, 8-way reduce, normalize, gamma*O + x.
// NOTE: no s_setprio (R13: spill on this structure).
__global__ __launch_bounds__(512, 4) void attn_fused_kernel(
    const short* __restrict__ Qp, const short* __restrict__ Kp,
    const unsigned char* __restrict__ VF8,
    const float* __restrict__ x, const float* __restrict__ gamma,
    float* __restrict__ out)
{
  __shared__ float lacc[8 * 2080];    // [w][q=32][65]  (pad kills conflicts)
  __shared__ float slsum[8 * 32];     // [w][q]

  const int tid  = threadIdx.x;
  const int w    = tid >> 6;          // key-slice 0..7
  const int lane = tid & 63;
  const int hi   = lane >> 5;
  const int ln   = lane & 31;
  const int q0   = blockIdx.x * 32;

  const short8 zero8 = {0,0,0,0,0,0,0,0};
  f32x16 zf16;
#pragma unroll
  for (int i = 0; i < 16; ++i) zf16[i] = 0.f;

  // Q fragment: B[k=8hi+e][q=ln]; hi half zero (d=8 padded to K=16)
  short8 qf = hi ? zero8
                 : *reinterpret_cast<const short8*>(Qp + (size_t)(q0 + ln) * 8);

  f32x16 acc0 = zf16, acc1 = zf16;   // c 0-31 / c 32-63
  float lsum = 0.f;

  const int kvlen = NTOK / 8;
  const int kv_lo = w * kvlen;
  const int nh    = kvlen / 32;      // 64 half-tiles of 32 keys

  const short* KP0 = Kp + ((size_t)kv_lo + ln) * 8;              // +h*256
  const unsigned char* VF0 = VF8 + (size_t)kv_lo * 64 + lane * 8; // +h*2048 B

  auto loadK = [&](int h, short8& kf) {
    kf = *reinterpret_cast<const short8*>(KP0 + (size_t)h * 256);
  };
  // 4 fp8 B-frags per half-tile (2 k-chunks x 2 c-chunks), 8B/lane each
  auto loadV = [&](int h, long (&vf)[4]) {
    const unsigned char* vp = VF0 + (size_t)h * 2048;
#pragma unroll
    for (int j = 0; j < 4; ++j)
      vf[j] = *reinterpret_cast<const long*>(vp + j * 512);
  };

  // exp + fp8-pack + pairwise f32 lsum tree for one half-tile's S
  auto expPack = [&](const f32x16& sv, long (&pa)[2]) {
    float e[16];
#pragma unroll
    for (int r = 0; r < 16; ++r) e[r] = fast_exp2(sv[r]);

    float t0 = (e[0] + e[1]) + (e[2] + e[3]);
    float t1 = (e[4] + e[5]) + (e[6] + e[7]);
    float t2 = (e[8] + e[9]) + (e[10] + e[11]);
    float t3 = (e[12] + e[13]) + (e[14] + e[15]);
    lsum += (t0 + t1) + (t2 + t3);

    unsigned u0 = pack_fp8x4(e[0],  e[1],  e[2],  e[3]);
    unsigned u1 = pack_fp8x4(e[4],  e[5],  e[6],  e[7]);
    unsigned u2 = pack_fp8x4(e[8],  e[9],  e[10], e[11]);
    unsigned u3 = pack_fp8x4(e[12], e[13], e[14], e[15]);
    pa[0] = (long)(((unsigned long long)u1 << 32) | u0);
    pa[1] = (long)(((unsigned long long)u3 << 32) | u2);
  };

  auto pvHalf = [&](const long (&pa)[2], const long (&vf)[4]) {
    acc0 = __builtin_amdgcn_mfma_f32_32x32x16_fp8_fp8(pa[0], vf[0], acc0, 0, 0, 0);
    acc1 = __builtin_amdgcn_mfma_f32_32x32x16_fp8_fp8(pa[0], vf[1], acc1, 0, 0, 0);
    acc0 = __builtin_amdgcn_mfma_f32_32x32x16_fp8_fp8(pa[1], vf[2], acc0, 0, 0, 0);
    acc1 = __builtin_amdgcn_mfma_f32_32x32x16_fp8_fp8(pa[1], vf[3], acc1, 0, 0, 0);
  };

  // prologue: halves 0,1 resident; S(0) in flight
  short8 kA, kB;
  long vA[4], vB[4];
  loadK(0, kA); loadV(0, vA);
  loadK(1, kB); loadV(1, vB);
  f32x16 svA = __builtin_amdgcn_mfma_f32_32x32x16_bf16(kA, qf, zf16, 0, 0, 0);
  f32x16 svB;

  for (int h = 0; h < nh; h += 2) {
    // ---- half h (consume svA, vA; issue S(h+1), loads h+2) ----
    svB = __builtin_amdgcn_mfma_f32_32x32x16_bf16(kB, qf, zf16, 0, 0, 0);
    { const int hp = (h + 2 < nh) ? h + 2 : nh - 1; loadK(hp, kA); }
    long pa[2];
    expPack(svA, pa);
    pvHalf(pa, vA);
    { const int hp = (h + 2 < nh) ? h + 2 : nh - 1; loadV(hp, vA); }

    // ---- half h+1 (consume svB, vB; issue S(h+2), loads h+3) ----
    svA = __builtin_amdgcn_mfma_f32_32x32x16_bf16(kA, qf, zf16, 0, 0, 0);
    { const int hp = (h + 3 < nh) ? h + 3 : nh - 1; loadK(hp, kB); }
    long pa2[2];
    expPack(svB, pa2);
    pvHalf(pa2, vB);
    { const int hp = (h + 3 < nh) ? h + 3 : nh - 1; loadV(hp, vB); }
  }

  // ---- epilogue: stage partials in LDS ----
  // C layout: qrow=(r&3)+8*(r>>2)+4*hi, col=ln (acc0) / 32+ln (acc1)
  float* la = &lacc[w * 2080];
#pragma unroll
  for (int r = 0; r < 16; ++r) {
    const int qrow = (r & 3) + 8 * (r >> 2) + 4 * hi;
    la[qrow * 65 + ln]      = acc0[r];
    la[qrow * 65 + 32 + ln] = acc1[r];
  }
  lsum += __shfl_xor(lsum, 32);      // combine hi halves (disjoint keys)
  if (lane < 32) slsum[w * 32 + ln] = lsum;
  __syncthreads();

  // ---- 8-way reduce + normalize + residual, c-major store ----
  const int q = tid & 31;
  float ls = 0.f;
#pragma unroll
  for (int w2 = 0; w2 < 8; ++w2) ls += slsum[w2 * 32 + q];
  const float inv = 1.f / ls;
  const float gam = gamma[0];

#pragma unroll
  for (int k = 0; k < 4; ++k) {
    const int c = (tid >> 5) + k * 16;
    float sum = 0.f;
#pragma unroll
    for (int w2 = 0; w2 < 8; ++w2) sum += lacc[w2 * 2080 + q * 65 + c];
    const size_t idx = (size_t)c * NTOK + q0 + q;
    out[idx] = gam * sum * inv + x[idx];
  }
}

extern "C" void kernel_launch(void* const* d_in, const int* in_sizes, int n_in,
                              void* d_out, int out_size, void* d_ws, size_t ws_size,
                              hipStream_t stream) {
  const float* x     = (const float*)d_in[0];
  const float* Wq    = (const float*)d_in[1];
  const float* bq    = (const float*)d_in[2];
  const float* Wk    = (const float*)d_in[3];
  const float* bk    = (const float*)d_in[4];
  const float* Wv    = (const float*)d_in[5];
  const float* bv    = (const float*)d_in[6];
  const float* gamma = (const float*)d_in[7];
  float* out = (float*)d_out;

  short* Qp = (short*)d_ws;                   // [N][8] bf16  (256 KB)
  short* Kp = Qp + (size_t)NTOK * 8;          // [N][8] bf16  (256 KB), sigma rows
  unsigned char* VF8 = (unsigned char*)(Kp + (size_t)NTOK * 8);  // fp8 V (1 MB)

  proj_all_kernel<<<NTOK / 32, 256, 0, stream>>>(x, Wq, bq, Wk, bk, Wv, bv,
                                                 Qp, Kp, VF8);
  attn_fused_kernel<<<NTOK / 32, 512, 0, stream>>>(Qp, Kp, VF8, x, gamma, out);
}